// Round 1
// baseline (792.055 us; speedup 1.0000x reference)
//
#include <hip/hip_runtime.h>

#define H 480
#define W 640
#define NP 256          // number of pairs
#define HW (H * W)
#define CHUNKS_PER_ROW (W / 4)          // 160 float4 chunks per row
#define BLOCKS_PER_PAIR 300             // 480*160 / 256

// ---------------- Kernel 1: 5x5 box average with replicate padding ----------
__global__ __launch_bounds__(256) void box_avg_kernel(const float* __restrict__ x,
                                                      float* __restrict__ box) {
    int idx = blockIdx.x * 256 + threadIdx.x;   // grid sized exactly HW/256
    int i = idx / W;
    int j = idx - i * W;
    float s = 0.f;
#pragma unroll
    for (int dy = -2; dy <= 2; ++dy) {
        int yy = min(max(i + dy, 0), H - 1);
        const float* row = x + yy * W;
#pragma unroll
        for (int dx = -2; dx <= 2; ++dx) {
            int xx = min(max(j + dx, 0), W - 1);
            s += row[xx];
        }
    }
    box[idx] = s * 0.04f;   // 1/25
}

// ---------------- Kernel 2: per-pair dual bilinear sample + difference ------
// grid = NP * BLOCKS_PER_PAIR blocks of 256 threads; each thread -> 4 px.
__global__ __launch_bounds__(256) void bad_desc_kernel(const float* __restrict__ box,
                                                       const float* __restrict__ po,
                                                       float* __restrict__ out) {
    int p     = blockIdx.x / BLOCKS_PER_PAIR;                    // uniform -> SGPR
    int local = (blockIdx.x % BLOCKS_PER_PAIR) * 256 + threadIdx.x; // chunk in pair
    int i = local / CHUNKS_PER_ROW;
    int j = (local - i * CHUNKS_PER_ROW) * 4;

    // pair_offsets[p][k][c]: c=0 -> dy, c=1 -> dx
    float dy1 = po[p * 4 + 0];
    float dx1 = po[p * 4 + 1];
    float dy2 = po[p * 4 + 2];
    float dx2 = po[p * 4 + 3];

    float fi = (float)i;

    // sample-1 rows
    float py1 = fminf(fmaxf(fi + dy1, 0.f), (float)(H - 1));
    int   ya0 = (int)py1;                 // py1 >= 0 -> trunc == floor
    float wy1 = py1 - (float)ya0;
    int   ya1 = min(ya0 + 1, H - 1);
    const float* r1a = box + ya0 * W;
    const float* r1b = box + ya1 * W;

    // sample-2 rows
    float py2 = fminf(fmaxf(fi + dy2, 0.f), (float)(H - 1));
    int   yb0 = (int)py2;
    float wy2 = py2 - (float)yb0;
    int   yb1 = min(yb0 + 1, H - 1);
    const float* r2a = box + yb0 * W;
    const float* r2b = box + yb1 * W;

    float4 res;
    float* rp = (float*)&res;
#pragma unroll
    for (int k = 0; k < 4; ++k) {
        float fj = (float)(j + k);

        // sample 1
        float px = fminf(fmaxf(fj + dx1, 0.f), (float)(W - 1));
        int   x0 = (int)px;
        float wx = px - (float)x0;
        int   x1 = min(x0 + 1, W - 1);
        float a0 = r1a[x0], a1 = r1a[x1];
        float b0 = r1b[x0], b1 = r1b[x1];
        float h0 = fmaf(wx, a1 - a0, a0);
        float h1 = fmaf(wx, b1 - b0, b0);
        float v1 = fmaf(wy1, h1 - h0, h0);

        // sample 2
        float qx = fminf(fmaxf(fj + dx2, 0.f), (float)(W - 1));
        int   u0 = (int)qx;
        float ux = qx - (float)u0;
        int   u1 = min(u0 + 1, W - 1);
        float c0 = r2a[u0], c1 = r2a[u1];
        float d0 = r2b[u0], d1 = r2b[u1];
        float g0 = fmaf(ux, c1 - c0, c0);
        float g1 = fmaf(ux, d1 - d0, d0);
        float v2 = fmaf(wy2, g1 - g0, g0);

        rp[k] = v1 - v2;
    }

    *(float4*)(out + ((size_t)p * HW + (size_t)i * W + (size_t)j)) = res;
}

extern "C" void kernel_launch(void* const* d_in, const int* in_sizes, int n_in,
                              void* d_out, int out_size, void* d_ws, size_t ws_size,
                              hipStream_t stream) {
    const float* x  = (const float*)d_in[0];   // [1,1,480,640]
    const float* po = (const float*)d_in[1];   // [256,2,2]
    float* out = (float*)d_out;                // [1,256,480,640]
    float* box = (float*)d_ws;                 // 480*640 floats = 1.23 MB scratch

    box_avg_kernel<<<HW / 256, 256, 0, stream>>>(x, box);
    bad_desc_kernel<<<NP * BLOCKS_PER_PAIR, 256, 0, stream>>>(box, po, out);
}

// Round 2
// 374.463 us; speedup vs baseline: 2.1152x; 2.1152x over previous
//
#include <hip/hip_runtime.h>

#define H 480
#define W 640
#define NP 256
#define HW (H * W)

// Interior: 8 px per thread, j in [32, 608) -> 72 groups/row, 72*480=34560 threads = 135 blocks/pair
#define ABLK 135
// Border: 1 px per thread, j in [0,32) U [608,640) -> 64 px/row, 64*480=30720 threads = 120 blocks/pair
#define BBLK 120
#define TOTAL_BLK (NP * (ABLK + BBLK))
#define A_TOTAL (NP * ABLK)

// ---------------- Kernel 1: 5x5 box average with replicate padding ----------
__global__ __launch_bounds__(256) void box_avg_kernel(const float* __restrict__ x,
                                                      float* __restrict__ box) {
    int idx = blockIdx.x * 256 + threadIdx.x;
    int i = idx / W;
    int j = idx - i * W;
    float s = 0.f;
#pragma unroll
    for (int dy = -2; dy <= 2; ++dy) {
        int yy = min(max(i + dy, 0), H - 1);
        const float* row = x + yy * W;
#pragma unroll
        for (int dx = -2; dx <= 2; ++dx) {
            int xx = min(max(j + dx, 0), W - 1);
            s += row[xx];
        }
    }
    box[idx] = s * 0.04f;
}

// ---- interior helper: 8-px horizontal+vertical lerp from 3 aligned float4 per row ----
template<int S>
__device__ __forceinline__ void sample8(const float4 Pa, const float4 Qa, const float4 Ra,
                                        const float4 Pb, const float4 Qb, const float4 Rb,
                                        float wx, float wy, float v[8]) {
    const float ca[12] = {Pa.x, Pa.y, Pa.z, Pa.w, Qa.x, Qa.y, Qa.z, Qa.w, Ra.x, Ra.y, Ra.z, Ra.w};
    const float cb[12] = {Pb.x, Pb.y, Pb.z, Pb.w, Qb.x, Qb.y, Qb.z, Qb.w, Rb.x, Rb.y, Rb.z, Rb.w};
#pragma unroll
    for (int k = 0; k < 8; ++k) {
        float ha = fmaf(wx, ca[S + k + 1] - ca[S + k], ca[S + k]);
        float hb = fmaf(wx, cb[S + k + 1] - cb[S + k], cb[S + k]);
        v[k] = fmaf(wy, hb - ha, ha);
    }
}

#define DISPATCH_S(sv, ...)                                  \
    switch (sv) {                                            \
        case 0:  sample8<0>(__VA_ARGS__); break;             \
        case 1:  sample8<1>(__VA_ARGS__); break;             \
        case 2:  sample8<2>(__VA_ARGS__); break;             \
        default: sample8<3>(__VA_ARGS__); break;             \
    }

__global__ __launch_bounds__(256) void bad_desc_kernel(const float* __restrict__ box,
                                                       const float* __restrict__ po,
                                                       float* __restrict__ out) {
    int b = blockIdx.x;
    if (b < A_TOTAL) {
        // ---------------- interior: vectorized, clamp-free in x ----------------
        int p = b / ABLK;
        int t = (b - p * ABLK) * 256 + threadIdx.x;
        int i = t / 72;
        int g = t - i * 72;
        int j = 32 + (g << 3);

        float dy1 = po[p * 4 + 0];
        float dx1 = po[p * 4 + 1];
        float dy2 = po[p * 4 + 2];
        float dx2 = po[p * 4 + 3];

        float fi = (float)i;
        float fj = (float)j;

        // ---- sample 1 ----
        float py1 = fminf(fmaxf(fi + dy1, 0.f), (float)(H - 1));
        int   ya0 = (int)py1;
        float wy1 = py1 - (float)ya0;
        int   ya1 = min(ya0 + 1, H - 1);

        float xf1 = fj + dx1;               // in (16, 624): no clamp possible
        float fl1 = floorf(xf1);
        int   x01 = (int)fl1;
        float wx1 = xf1 - fl1;
        int   s1  = __builtin_amdgcn_readfirstlane(x01 & 3);  // wave-uniform
        int   m1  = x01 - (x01 & 3);

        const float4* r1a = (const float4*)(box + ya0 * W + m1);
        const float4* r1b = (const float4*)(box + ya1 * W + m1);
        float4 Pa = r1a[0], Qa = r1a[1], Ra = r1a[2];
        float4 Pb = r1b[0], Qb = r1b[1], Rb = r1b[2];

        float v1[8];
        DISPATCH_S(s1, Pa, Qa, Ra, Pb, Qb, Rb, wx1, wy1, v1);

        // ---- sample 2 ----
        float py2 = fminf(fmaxf(fi + dy2, 0.f), (float)(H - 1));
        int   yb0 = (int)py2;
        float wy2 = py2 - (float)yb0;
        int   yb1 = min(yb0 + 1, H - 1);

        float xf2 = fj + dx2;
        float fl2 = floorf(xf2);
        int   x02 = (int)fl2;
        float wx2 = xf2 - fl2;
        int   s2  = __builtin_amdgcn_readfirstlane(x02 & 3);
        int   m2  = x02 - (x02 & 3);

        const float4* r2a = (const float4*)(box + yb0 * W + m2);
        const float4* r2b = (const float4*)(box + yb1 * W + m2);
        float4 Pc = r2a[0], Qc = r2a[1], Rc = r2a[2];
        float4 Pd = r2b[0], Qd = r2b[1], Rd = r2b[2];

        float v2[8];
        DISPATCH_S(s2, Pc, Qc, Rc, Pd, Qd, Rd, wx2, wy2, v2);

        float* o = out + ((size_t)p * HW + (size_t)i * W + (size_t)j);
        float4 o0 = {v1[0] - v2[0], v1[1] - v2[1], v1[2] - v2[2], v1[3] - v2[3]};
        float4 o1 = {v1[4] - v2[4], v1[5] - v2[5], v1[6] - v2[6], v1[7] - v2[7]};
        *(float4*)(o)     = o0;
        *(float4*)(o + 4) = o1;
    } else {
        // ---------------- border: 1 px per lane, fully clamped scalar path ----------------
        int b2 = b - A_TOTAL;
        int p = b2 / BBLK;
        int t = (b2 - p * BBLK) * 256 + threadIdx.x;
        int i = t >> 6;          // 0..479
        int c = t & 63;
        int j = (c < 32) ? c : 576 + c;   // 0..31 or 608..639

        float dy1 = po[p * 4 + 0];
        float dx1 = po[p * 4 + 1];
        float dy2 = po[p * 4 + 2];
        float dx2 = po[p * 4 + 3];

        float fi = (float)i;
        float fj = (float)j;

        // sample 1
        float py1 = fminf(fmaxf(fi + dy1, 0.f), (float)(H - 1));
        int   ya0 = (int)py1;
        float wy1 = py1 - (float)ya0;
        int   ya1 = min(ya0 + 1, H - 1);
        const float* r1a = box + ya0 * W;
        const float* r1b = box + ya1 * W;

        float px = fminf(fmaxf(fj + dx1, 0.f), (float)(W - 1));
        int   x0 = (int)px;
        float wx = px - (float)x0;
        int   x1 = min(x0 + 1, W - 1);
        float a0 = r1a[x0], a1 = r1a[x1];
        float b0 = r1b[x0], b1 = r1b[x1];
        float h0 = fmaf(wx, a1 - a0, a0);
        float h1 = fmaf(wx, b1 - b0, b0);
        float v1 = fmaf(wy1, h1 - h0, h0);

        // sample 2
        float py2 = fminf(fmaxf(fi + dy2, 0.f), (float)(H - 1));
        int   yb0 = (int)py2;
        float wy2 = py2 - (float)yb0;
        int   yb1 = min(yb0 + 1, H - 1);
        const float* r2a = box + yb0 * W;
        const float* r2b = box + yb1 * W;

        float qx = fminf(fmaxf(fj + dx2, 0.f), (float)(W - 1));
        int   u0 = (int)qx;
        float ux = qx - (float)u0;
        int   u1 = min(u0 + 1, W - 1);
        float c0 = r2a[u0], c1 = r2a[u1];
        float d0 = r2b[u0], d1 = r2b[u1];
        float g0 = fmaf(ux, c1 - c0, c0);
        float g1 = fmaf(ux, d1 - d0, d0);
        float v2 = fmaf(wy2, g1 - g0, g0);

        out[(size_t)p * HW + (size_t)i * W + (size_t)j] = v1 - v2;
    }
}

extern "C" void kernel_launch(void* const* d_in, const int* in_sizes, int n_in,
                              void* d_out, int out_size, void* d_ws, size_t ws_size,
                              hipStream_t stream) {
    const float* x  = (const float*)d_in[0];   // [1,1,480,640]
    const float* po = (const float*)d_in[1];   // [256,2,2]
    float* out = (float*)d_out;                // [1,256,480,640]
    float* box = (float*)d_ws;                 // 480*640 floats scratch

    box_avg_kernel<<<HW / 256, 256, 0, stream>>>(x, box);
    bad_desc_kernel<<<TOTAL_BLK, 256, 0, stream>>>(box, po, out);
}